// Round 11
// baseline (183.691 us; speedup 1.0000x reference)
//
#include <hip/hip_runtime.h>
#include <math.h>

#define Bn 16
#define Ln 1444      // 38*38
#define NCn 21
#define Cn 64
#define NBn 23       // 64-position tiles
#define KC 1344      // 21*64
#define RFIN 16      // final-phase amplification (measurement round)

// ---- Kernel B: classify (LDS-staged) + transpose + per-block class sums ---
// (R6 version, measured ~5-7 us)
__global__ __launch_bounds__(256) void kB(const float* __restrict__ cls_pred,
                                          const float* __restrict__ source,
                                          int* __restrict__ cls_idx,
                                          float* __restrict__ src_out,
                                          float* __restrict__ bs) {
    int b = blockIdx.x / NBn, m = blockIdx.x % NBn;
    int base = m * 64;
    int lane = threadIdx.x & 63, grp = threadIdx.x >> 6;
    __shared__ float sh[9536];
    __shared__ int cls[64];
    float (*tile)[65] = (float(*)[65])sh;   // [64][65]
    float* clsP = sh + 4160;                // 5376 floats, dead after classify
    float* WS   = sh + 4160;                // [4][1344] overlays clsP

#pragma unroll
    for (int cc = 0; cc < 16; cc++) {
        int c = grp * 16 + cc;
        float v = 0.f;
        if (base + lane < Ln) v = source[((size_t)b * Cn + c) * Ln + base + lane];
        tile[c][lane] = v;
    }
    {
        const float4* gp = reinterpret_cast<const float4*>(cls_pred + ((size_t)b * Ln + base) * 84);
        int lim4 = (Ln - base) * 21;
#pragma unroll
        for (int it = 0; it < 6; it++) {
            int f4 = threadIdx.x + it * 256;
            if (f4 < 1344) {
                float4 v = (f4 < lim4) ? gp[f4] : make_float4(0.f, 0.f, 0.f, 0.f);
                reinterpret_cast<float4*>(clsP)[f4] = v;
            }
        }
    }
    __syncthreads();   // S1

    {
        int p = threadIdx.x >> 2, a = threadIdx.x & 3;
        bool valid = (base + p < Ln);
        const float* q = clsP + p * 84 + a * 21;
        float x[21];
#pragma unroll
        for (int i = 0; i < 21; i++) x[i] = q[i];
        float mx = x[0];
#pragma unroll
        for (int i = 1; i < 21; i++) mx = fmaxf(mx, x[i]);
        float s = 0.f;
#pragma unroll
        for (int i = 0; i < 21; i++) { x[i] = expf(x[i] - mx); s += x[i]; }
        float best = -1.f; int bi = 0;
#pragma unroll
        for (int i = 0; i < 21; i++) {
            float sm = x[i] / s;                     // exact per-element division (matches ref)
            if (sm > best) { best = sm; bi = a * 21 + i; }
        }
#pragma unroll
        for (int d = 1; d <= 2; d <<= 1) {
            float ob = __shfl_xor(best, d);
            int oi = __shfl_xor(bi, d);
            if (ob > best || (ob == best && oi < bi)) { best = ob; bi = oi; }
        }
        if (a == 0) {
            if (valid) { int k = bi % 21; cls[p] = k; cls_idx[b * Ln + base + p] = k; }
            else cls[p] = 255;
        }
    }
    __syncthreads();   // S2: cls ready, clsP dead

    float cs[21];
#pragma unroll
    for (int k = 0; k < 21; k++) cs[k] = 0.f;
#pragma unroll
    for (int jj = 0; jj < 16; jj++) {
        int j = grp * 16 + jj;
        float v = tile[lane][j];                 // stride-65: conflict-free
        if (base + j < Ln) src_out[((size_t)b * Ln + base + j) * Cn + lane] = v;
        int k = cls[j];                          // wave-uniform broadcast
#pragma unroll
        for (int kk = 0; kk < 21; kk++) cs[kk] += (kk == k) ? v : 0.f;
    }
#pragma unroll
    for (int kk = 0; kk < 21; kk++) WS[grp * KC + kk * 64 + lane] = cs[kk];
    __syncthreads();   // S3

    for (int i = threadIdx.x; i < KC; i += 256) {
        float v = WS[i] + WS[KC + i] + WS[2 * KC + i] + WS[3 * KC + i];
        bs[((size_t)b * NBn + m) * KC + i] = v;
    }
}

// ---- Kernel C (R9 structure) with FINAL PHASE amplified x16 ---------------
__global__ __launch_bounds__(512, 2) void kC(const float* __restrict__ src,
                                             const int* __restrict__ cls_idx,
                                             const float* __restrict__ R,
                                             const float* __restrict__ bs,
                                             float* __restrict__ fused) {
    int b = blockIdx.x / NBn, m = blockIdx.x % NBn;
    int base = m * 64;
    int lane = threadIdx.x & 63, grp = threadIdx.x >> 6;   // 8 waves, 8 pos each
    __shared__ float PS[KC];       // prefix over tiles < m
    __shared__ float Tt[KC];       // batch totals
    __shared__ float WS[8][KC];    // per-wave (8-position) class sums
    __shared__ float2 Q[441];      // (R[a][k]-R[k][a], R[k][a])
    __shared__ int cls[64];

    // own 8 positions into registers (coalesced rows)
    float sT[8];
#pragma unroll
    for (int t = 0; t < 8; t++) {
        int i = grp * 8 + t;
        sT[t] = (base + i < Ln) ? src[((size_t)b * Ln + base + i) * Cn + lane] : 0.f;
    }
    if (threadIdx.x < 64) {
        int k = 255;
        if (base + (int)threadIdx.x < Ln) k = cls_idx[b * Ln + base + threadIdx.x];
        cls[threadIdx.x] = k;
    }
    if (threadIdx.x < 441) {
        int a = threadIdx.x / 21, k = threadIdx.x % 21;
        float rak = R[a * 21 + k], rka = R[k * 21 + a];
        Q[threadIdx.x] = make_float2(rak - rka, rka);
    }
    // stream bs: threads 0..335 each own one float4 group, 23 batched loads
    if (threadIdx.x < KC / 4) {
        int g = threadIdx.x;
        float rx = 0.f, ry = 0.f, rz = 0.f, rw = 0.f;
        float px = 0.f, py = 0.f, pz = 0.f, pw = 0.f;
#pragma unroll
        for (int mm = 0; mm < NBn; mm++) {
            float4 v = *reinterpret_cast<const float4*>(&bs[((size_t)b * NBn + mm) * KC + g * 4]);
            rx += v.x; ry += v.y; rz += v.z; rw += v.w;
            if (mm < m) { px += v.x; py += v.y; pz += v.z; pw += v.w; }  // uniform branch
        }
        PS[g * 4] = px; PS[g * 4 + 1] = py; PS[g * 4 + 2] = pz; PS[g * 4 + 3] = pw;
        Tt[g * 4] = rx; Tt[g * 4 + 1] = ry; Tt[g * 4 + 2] = rz; Tt[g * 4 + 3] = rw;
    }
    __syncthreads();   // S1: PS/Tt/Q/cls ready

    // own-chunk (8 positions) class sums -> WS
    {
        float cs[21];
#pragma unroll
        for (int k = 0; k < 21; k++) cs[k] = 0.f;
#pragma unroll
        for (int t = 0; t < 8; t++) {
            int j = grp * 8 + t;
            int k = cls[j];                      // wave-uniform broadcast
#pragma unroll
            for (int kk = 0; kk < 21; kk++) cs[kk] += (kk == k) ? sT[t] : 0.f;
        }
#pragma unroll
        for (int kk = 0; kk < 21; kk++) WS[grp][kk * 64 + lane] = cs[kk];
    }
    __syncthreads();   // S2: WS ready

    // ===== AMPLIFIED FINAL PHASE (x RFIN): ms/Tc init + combine loop =====
    // Loop body only READS LDS and writes identical values to fused -> idempotent.
    for (int rep = 0; rep < RFIN; rep++) {
        float Tc[21];
#pragma unroll
        for (int k = 0; k < 21; k++) Tc[k] = Tt[k * 64 + lane];

        float ms[21];
#pragma unroll
        for (int k = 0; k < 21; k++) {
            float x = PS[k * 64 + lane];
#pragma unroll
            for (int g = 0; g < 7; g++)
                if (g < grp) x += WS[g][k * 64 + lane];
            ms[k] = x;
        }

        int nvalid = (Ln - base < 64) ? (Ln - base) : 64;
        for (int t = 0; t < 8; t++) {
            int i = grp * 8 + t;
            if (i >= nvalid) break;
            int ci = cls[i];                     // wave-uniform
            float sv = sT[t];
            float rdiag = Q[ci * 22].y;
            float accA = (((ci != 0) ? 1.f : 0.f) - rdiag) * sv;
            float accB = 0.f;
#pragma unroll
            for (int k = 0; k < 21; k++) {
                float2 w = Q[ci * 21 + k];       // broadcast ds_read_b64
                accA = fmaf(w.x, ms[k], accA);
                accB = fmaf(w.y, Tc[k], accB);
            }
            fused[((size_t)b * Ln + base + i) * Cn + lane] = accA + accB;
#pragma unroll
            for (int kk = 0; kk < 21; kk++) ms[kk] += (kk == ci) ? sv : 0.f;
        }
    }
}

extern "C" void kernel_launch(void* const* d_in, const int* in_sizes, int n_in,
                              void* d_out, int out_size, void* d_ws, size_t ws_size,
                              hipStream_t stream) {
    const float* cls_pred = (const float*)d_in[0];
    const float* source = (const float*)d_in[1];
    const float* cls_r_prob = (const float*)d_in[2];

    float* fused = (float*)d_out;
    float* src_out = fused + (size_t)Bn * Ln * Cn;

    char* w = (char*)d_ws;
    int* cls_idx = (int*)w;                                    // 92416 B
    size_t off = ((size_t)Bn * Ln * 4 + 1023) & ~(size_t)1023;
    float* bs = (float*)(w + off);                             // 16*23*1344*4 = 1.98 MB

    hipLaunchKernelGGL(kB, dim3(Bn * NBn), dim3(256), 0, stream,
                       cls_pred, source, cls_idx, src_out, bs);
    hipLaunchKernelGGL(kC, dim3(Bn * NBn), dim3(512), 0, stream,
                       src_out, cls_idx, cls_r_prob, bs, fused);
}

// Round 13
// 29.173 us; speedup vs baseline: 6.2966x; 6.2966x over previous
//
#include <hip/hip_runtime.h>
#include <math.h>

#define Bn 16
#define Ln 1444      // 38*38
#define NCn 21
#define Cn 64
#define NBn 23       // 64-position tiles
#define KC 1344      // 21*64

// ---- Kernel B: classify (LDS-staged) + transpose + per-block class sums ---
// XCD-local mapping: b = bid%16, m = bid/16 -> all 23 blocks of a batch on 1 XCD.
__global__ __launch_bounds__(256) void kB(const float* __restrict__ cls_pred,
                                          const float* __restrict__ source,
                                          const float* __restrict__ R,
                                          int* __restrict__ cls_idx,
                                          float* __restrict__ src_out,
                                          float* __restrict__ bs,
                                          float2* __restrict__ Gg) {
    int b = blockIdx.x & 15, m = blockIdx.x >> 4;
    int base = m * 64;
    int lane = threadIdx.x & 63, grp = threadIdx.x >> 6;
    __shared__ float sh[9536];
    __shared__ int cls[64];
    float (*tile)[65] = (float(*)[65])sh;   // [64][65]
    float* clsP = sh + 4160;                // 5376 floats, dead after classify
    float* WS   = sh + 4160;                // [4][1344] overlays clsP

    // block 0 publishes the G table (Gx = R[a][k]-R[k][a], Gy = R[k][a])
    // NOTE: 256-thread block -> strided loop (R12 bug: guard <441 left 256..440 unwritten)
    if (blockIdx.x == 0) {
        for (int i = threadIdx.x; i < 441; i += 256) {
            int a = i / 21, k = i % 21;
            float rak = R[a * 21 + k], rka = R[k * 21 + a];
            Gg[i] = make_float2(rak - rka, rka);
        }
    }

#pragma unroll
    for (int cc = 0; cc < 16; cc++) {
        int c = grp * 16 + cc;
        float v = 0.f;
        if (base + lane < Ln) v = source[((size_t)b * Cn + c) * Ln + base + lane];
        tile[c][lane] = v;
    }
    {
        const float4* gp = reinterpret_cast<const float4*>(cls_pred + ((size_t)b * Ln + base) * 84);
        int lim4 = (Ln - base) * 21;
#pragma unroll
        for (int it = 0; it < 6; it++) {
            int f4 = threadIdx.x + it * 256;
            if (f4 < 1344) {
                float4 v = (f4 < lim4) ? gp[f4] : make_float4(0.f, 0.f, 0.f, 0.f);
                reinterpret_cast<float4*>(clsP)[f4] = v;
            }
        }
    }
    __syncthreads();   // S1

    {
        int p = threadIdx.x >> 2, a = threadIdx.x & 3;
        bool valid = (base + p < Ln);
        const float* q = clsP + p * 84 + a * 21;
        float x[21];
#pragma unroll
        for (int i = 0; i < 21; i++) x[i] = q[i];
        float mx = x[0];
#pragma unroll
        for (int i = 1; i < 21; i++) mx = fmaxf(mx, x[i]);
        float s = 0.f;
#pragma unroll
        for (int i = 0; i < 21; i++) { x[i] = expf(x[i] - mx); s += x[i]; }
        float best = -1.f; int bi = 0;
#pragma unroll
        for (int i = 0; i < 21; i++) {
            float sm = x[i] / s;                     // exact per-element division (matches ref)
            if (sm > best) { best = sm; bi = a * 21 + i; }
        }
#pragma unroll
        for (int d = 1; d <= 2; d <<= 1) {
            float ob = __shfl_xor(best, d);
            int oi = __shfl_xor(bi, d);
            if (ob > best || (ob == best && oi < bi)) { best = ob; bi = oi; }
        }
        if (a == 0) {
            if (valid) { int k = bi % 21; cls[p] = k; cls_idx[b * Ln + base + p] = k; }
            else cls[p] = 255;
        }
    }
    __syncthreads();   // S2: cls ready, clsP dead

    float cs[21];
#pragma unroll
    for (int k = 0; k < 21; k++) cs[k] = 0.f;
#pragma unroll
    for (int jj = 0; jj < 16; jj++) {
        int j = grp * 16 + jj;
        float v = tile[lane][j];                 // stride-65: conflict-free
        if (base + j < Ln) src_out[((size_t)b * Ln + base + j) * Cn + lane] = v;
        int k = cls[j];                          // wave-uniform broadcast
#pragma unroll
        for (int kk = 0; kk < 21; kk++) cs[kk] += (kk == k) ? v : 0.f;
    }
#pragma unroll
    for (int kk = 0; kk < 21; kk++) WS[grp * KC + kk * 64 + lane] = cs[kk];
    __syncthreads();   // S3

    for (int i = threadIdx.x; i < KC; i += 256) {
        float v = WS[i] + WS[KC + i] + WS[2 * KC + i] + WS[3 * KC + i];
        bs[((size_t)b * NBn + m) * KC + i] = v;
    }
}

// ---- Kernel C: scalar-Q combine, wave-constant msW, zero LDS in hot loop --
// LDS: PS 5.4K + Tt 5.4K + WS[8] 43K + cls 256B  (~54 KB, 2 blk/CU)
__global__ __launch_bounds__(512, 2) void kC(const float* __restrict__ src,
                                             const int* __restrict__ cls_idx,
                                             const float2* __restrict__ Gg,
                                             const float* __restrict__ bs,
                                             float* __restrict__ fused) {
    int b = blockIdx.x & 15, m = blockIdx.x >> 4;
    int base = m * 64;
    int lane = threadIdx.x & 63, grp = threadIdx.x >> 6;   // 8 waves, 8 pos each
    __shared__ float PS[KC];       // prefix over tiles < m
    __shared__ float Tt[KC];       // batch totals
    __shared__ float WS[8][KC];    // per-wave class sums -> exclusive prefix in-place
    __shared__ int cls[64];

    // own 8 positions into registers (coalesced rows)
    float sT[8];
#pragma unroll
    for (int t = 0; t < 8; t++) {
        int i = grp * 8 + t;
        sT[t] = (base + i < Ln) ? src[((size_t)b * Ln + base + i) * Cn + lane] : 0.f;
    }
    if (threadIdx.x < 64) {
        int k = 0;                               // invalid -> class 0 (sT=0, harmless)
        if (base + (int)threadIdx.x < Ln) k = cls_idx[b * Ln + base + threadIdx.x];
        cls[threadIdx.x] = k;
    }
    // stream bs: threads 0..335 each own one float4 group, 23 batched loads (L2-local)
    if (threadIdx.x < KC / 4) {
        int g = threadIdx.x;
        float rx = 0.f, ry = 0.f, rz = 0.f, rw = 0.f;
        float px = 0.f, py = 0.f, pz = 0.f, pw = 0.f;
#pragma unroll
        for (int mm = 0; mm < NBn; mm++) {
            float4 v = *reinterpret_cast<const float4*>(&bs[((size_t)b * NBn + mm) * KC + g * 4]);
            rx += v.x; ry += v.y; rz += v.z; rw += v.w;
            if (mm < m) { px += v.x; py += v.y; pz += v.z; pw += v.w; }  // uniform branch
        }
        PS[g * 4] = px; PS[g * 4 + 1] = py; PS[g * 4 + 2] = pz; PS[g * 4 + 3] = pw;
        Tt[g * 4] = rx; Tt[g * 4 + 1] = ry; Tt[g * 4 + 2] = rz; Tt[g * 4 + 3] = rw;
    }
    __syncthreads();   // S1: PS/Tt/cls ready

    // wave classes into registers (wave-uniform values)
    int cj[8];
#pragma unroll
    for (int j = 0; j < 8; j++) cj[j] = cls[grp * 8 + j];

    // own-chunk (8 positions) class sums -> WS[grp]
    {
        float cs[21];
#pragma unroll
        for (int k = 0; k < 21; k++) cs[k] = 0.f;
#pragma unroll
        for (int t = 0; t < 8; t++) {
            int k = cj[t];
#pragma unroll
            for (int kk = 0; kk < 21; kk++) cs[kk] += (kk == k) ? sT[t] : 0.f;
        }
#pragma unroll
        for (int kk = 0; kk < 21; kk++) WS[grp][kk * 64 + lane] = cs[kk];
    }
    __syncthreads();   // S2: WS rows complete

    // cooperative exclusive prefix over 8 wave rows, seeded with PS
    for (int i = threadIdx.x; i < KC; i += 512) {
        float run = PS[i];
#pragma unroll
        for (int g = 0; g < 8; g++) {
            float w = WS[g][i];
            WS[g][i] = run;
            run += w;
        }
    }
    __syncthreads();   // S3: WS[g] = class-prefix before wave g's positions

    // registers: totals column + own wave's msW
    float Tc[21], msW[21];
#pragma unroll
    for (int k = 0; k < 21; k++) Tc[k] = Tt[k * 64 + lane];
#pragma unroll
    for (int k = 0; k < 21; k++) msW[k] = WS[grp][k * 64 + lane];

    // 8 independent positions; all coefficients via wave-uniform scalar loads
    int nvalid = (Ln - base < 64) ? (Ln - base) : 64;
#pragma unroll
    for (int t = 0; t < 8; t++) {
        int i = grp * 8 + t;
        if (i < nvalid) {                        // wave-uniform branch
            int cis = __builtin_amdgcn_readfirstlane(cj[t]);
            const float2* grow = Gg + cis * 21;
            float sv = sT[t];
            float accA = (((cis != 0) ? 1.f : 0.f) - grow[cis].y) * sv;
            float accB = 0.f;
#pragma unroll
            for (int k = 0; k < 21; k++) {
                float2 w = grow[k];              // s_load through K$ (wave-uniform)
                accA = fmaf(w.x, msW[k], accA);
                accB = fmaf(w.y, Tc[k], accB);
            }
#pragma unroll
            for (int j = 0; j < 8; j++)          // triangular j < t (static unroll)
                if (j < t) {
                    int cjs = __builtin_amdgcn_readfirstlane(cj[j]);
                    accA = fmaf(grow[cjs].x, sT[j], accA);
                }
            fused[((size_t)b * Ln + base + i) * Cn + lane] = accA + accB;
        }
    }
}

extern "C" void kernel_launch(void* const* d_in, const int* in_sizes, int n_in,
                              void* d_out, int out_size, void* d_ws, size_t ws_size,
                              hipStream_t stream) {
    const float* cls_pred = (const float*)d_in[0];
    const float* source = (const float*)d_in[1];
    const float* cls_r_prob = (const float*)d_in[2];

    float* fused = (float*)d_out;
    float* src_out = fused + (size_t)Bn * Ln * Cn;

    char* w = (char*)d_ws;
    int* cls_idx = (int*)w;                                    // 92416 B
    size_t off = ((size_t)Bn * Ln * 4 + 1023) & ~(size_t)1023;
    float* bs = (float*)(w + off);                             // 16*23*1344*4 = 1978368 B
    float2* Gg = (float2*)(w + off + (size_t)Bn * NBn * KC * 4);  // 441*8 B

    hipLaunchKernelGGL(kB, dim3(Bn * NBn), dim3(256), 0, stream,
                       cls_pred, source, cls_r_prob, cls_idx, src_out, bs, Gg);
    hipLaunchKernelGGL(kC, dim3(Bn * NBn), dim3(512), 0, stream,
                       src_out, cls_idx, Gg, bs, fused);
}